// Round 1
// baseline (259.592 us; speedup 1.0000x reference)
//
#include <hip/hip_runtime.h>
#include <hip/hip_bf16.h>

typedef __bf16 bf16_t;
typedef bf16_t bf16x8 __attribute__((ext_vector_type(8)));
typedef float f32x4 __attribute__((ext_vector_type(4)));

#define H 256
#define SEQ 4096
#define BSZ 32
#define T_TOK 64          // tokens per block
#define ROWS 80           // padded rows for hbf/AB (5 M-tiles of 16)
#define VROWS 66          // valid rows: tokens t0-1 .. t0+64
#define HB_STRIDE 264     // bf16 elems per row (+8 pad: row step = +4 banks)
#define AB_STRIDE 520     // 512 feats + 8 pad
#define S_STRIDE 264

// LDS layout (bf16 element offsets)
#define OFF_HBF 0
#define OFF_AB  (ROWS * HB_STRIDE)                  // 21120
#define OFF_S   (OFF_AB + ROWS * AB_STRIDE)         // 62720
#define SMEM_ELEMS (OFF_S + T_TOK * S_STRIDE)       // 79616 elems
#define SMEM_BYTES (SMEM_ELEMS * 2)                 // 159232 B (<160 KiB)
#define OFF_AGG OFF_AB                              // aliases AB (dead)
#define OFF_HN  (OFF_AB + T_TOK * S_STRIDE)         // 38016 (after AGG)

// ws layout (bf16 element offsets): transposed weights W^T[n][k]
#define WABT  0           // [512][256]
#define W2T   131072      // [256][256]
#define WN1AT 196608
#define WN1BT 262144
#define WN2T  327680
#define WS_ELEMS 393216

// ---- prepass: f32 weights -> bf16 transposed in ws ----
__global__ void wprep(const float* __restrict__ ew1, const float* __restrict__ ew2,
                      const float* __restrict__ nw1, const float* __restrict__ nw2,
                      bf16_t* __restrict__ wsw) {
    int idx = blockIdx.x * 256 + threadIdx.x;   // 0..393215, output-linear
    float v;
    if (idx < W2T) {                      // WabT[n][k]
        int n = idx >> 8, k = idx & 255;
        v = (n < 256) ? ew1[k * 256 + n] : ew1[(256 + k) * 256 + (n - 256)];
    } else if (idx < WN1AT) {             // W2T[n][k] = ew2[k][n]
        int r = idx - W2T; int n = r >> 8, k = r & 255;
        v = ew2[k * 256 + n];
    } else if (idx < WN1BT) {             // Wn1aT[n][k] = nw1[k][n]
        int r = idx - WN1AT; int n = r >> 8, k = r & 255;
        v = nw1[k * 256 + n];
    } else if (idx < WN2T) {              // Wn1bT[n][k] = nw1[256+k][n]
        int r = idx - WN1BT; int n = r >> 8, k = r & 255;
        v = nw1[(256 + k) * 256 + n];
    } else {                              // Wn2T[n][k] = nw2[k][n]
        int r = idx - WN2T; int n = r >> 8, k = r & 255;
        v = nw2[k * 256 + n];
    }
    wsw[idx] = (bf16_t)v;
}

// ---- fused GraphNet layer ----
__launch_bounds__(512, 2)
__global__ void gnl_kernel(const float* __restrict__ h, const float* __restrict__ mask,
                           const float* __restrict__ eb1, const float* __restrict__ eb2,
                           const float* __restrict__ nb1, const float* __restrict__ nb2,
                           const bf16_t* __restrict__ wsw, float* __restrict__ out) {
    extern __shared__ bf16_t sm[];
    bf16_t* hbf = sm + OFF_HBF;   // [ROWS][HB_STRIDE], row r <-> token t0-1+r
    bf16_t* AB  = sm + OFF_AB;    // [ROWS][AB_STRIDE]: cols 0..255 = A, 256..511 = B
    bf16_t* S   = sm + OFF_S;     // [T_TOK][S_STRIDE]
    bf16_t* AGG = sm + OFF_AGG;   // [T_TOK][S_STRIDE] (aliases AB)
    bf16_t* HN  = sm + OFF_HN;    // [T_TOK][S_STRIDE]

    const int tid   = threadIdx.x;
    const int lane  = tid & 63;
    const int w     = tid >> 6;           // wave 0..7
    const int batch = blockIdx.x >> 6;
    const int tile  = blockIdx.x & 63;
    const int t0    = tile * T_TOK;
    const long baseTok = (long)batch * SEQ;

    const int lr = lane & 15;             // A-row / B-col / C-col in tile
    const int lk = (lane >> 4) << 3;      // k offset {0,8,16,24}
    const int crb = (lane >> 4) << 2;     // C row base {0,4,8,12}

    // ---------- Phase 0: stage h -> bf16 LDS (zero-padded) ----------
    for (int c = tid; c < ROWS * 32; c += 512) {
        int r = c >> 5;
        int fc = (c & 31) << 3;
        int t = t0 - 1 + r;
        bf16x8 vals;
        if (r < VROWS && t >= 0 && t < SEQ) {
            const float* src = h + (((long)(baseTok + t)) << 8) + fc;
            float4 x0 = ((const float4*)src)[0];
            float4 x1 = ((const float4*)src)[1];
            vals[0] = (bf16_t)x0.x; vals[1] = (bf16_t)x0.y;
            vals[2] = (bf16_t)x0.z; vals[3] = (bf16_t)x0.w;
            vals[4] = (bf16_t)x1.x; vals[5] = (bf16_t)x1.y;
            vals[6] = (bf16_t)x1.z; vals[7] = (bf16_t)x1.w;
        } else {
#pragma unroll
            for (int j = 0; j < 8; ++j) vals[j] = (bf16_t)0.0f;
        }
        *(bf16x8*)(hbf + r * HB_STRIDE + fc) = vals;
    }
    __syncthreads();

    // ---------- Phase 1: AB = hbf @ [w1a | w1b]  (N = 512) ----------
    for (int i = 0; i < 4; ++i) {
        int nt = (w << 2) + i;            // 0..31
        int n0 = nt << 4;
        bf16x8 bfr[8];
        const bf16_t* wb = wsw + WABT + ((n0 + lr) << 8) + lk;
#pragma unroll
        for (int ks = 0; ks < 8; ++ks) bfr[ks] = *(const bf16x8*)(wb + (ks << 5));
        for (int mt = 0; mt < 5; ++mt) {
            f32x4 acc = {0.f, 0.f, 0.f, 0.f};
            const bf16_t* pa = hbf + (mt * 16 + lr) * HB_STRIDE + lk;
#pragma unroll
            for (int ks = 0; ks < 8; ++ks) {
                bf16x8 a = *(const bf16x8*)(pa + (ks << 5));
                acc = __builtin_amdgcn_mfma_f32_16x16x32_bf16(a, bfr[ks], acc, 0, 0, 0);
            }
            int rbase = mt * 16 + crb;
#pragma unroll
            for (int j = 0; j < 4; ++j)
                AB[(rbase + j) * AB_STRIDE + n0 + lr] = (bf16_t)acc[j];
        }
    }
    __syncthreads();

    // ---------- S pass: S[i] = relu(A[i]+B[i+1]+b1)*L + relu(A[i+2]+B[i+1]+b1)*R ----------
    for (int c = tid; c < T_TOK * 32; c += 512) {
        int i = c >> 5;
        int fc = (c & 31) << 3;
        int t = t0 + i;
        float bl = (t >= 1) ? 1.f : 0.f;
        float br = (t <= SEQ - 2) ? 1.f : 0.f;
        bf16x8 aL = *(const bf16x8*)(AB + i * AB_STRIDE + fc);
        bf16x8 aR = *(const bf16x8*)(AB + (i + 2) * AB_STRIDE + fc);
        bf16x8 bC = *(const bf16x8*)(AB + (i + 1) * AB_STRIDE + 256 + fc);
        float4 b1a = *(const float4*)(eb1 + fc);
        float4 b1b = *(const float4*)(eb1 + fc + 4);
        bf16x8 sv;
#pragma unroll
        for (int j = 0; j < 8; ++j) {
            float b1f = (j < 4) ? ((const float*)&b1a)[j] : ((const float*)&b1b)[j - 4];
            float x = (float)bC[j] + b1f;
            float l = fmaxf((float)aL[j] + x, 0.f) * bl;
            float r = fmaxf((float)aR[j] + x, 0.f) * br;
            sv[j] = (bf16_t)(l + r);
        }
        *(bf16x8*)(S + i * S_STRIDE + fc) = sv;
    }
    __syncthreads();

    // ---------- Phase 2: AGG = S @ w2 + cnt*b2 ----------
    for (int i = 0; i < 2; ++i) {
        int nt = (w << 1) + i;            // 0..15
        int n0 = nt << 4;
        bf16x8 bfr[8];
        const bf16_t* wb = wsw + W2T + ((n0 + lr) << 8) + lk;
#pragma unroll
        for (int ks = 0; ks < 8; ++ks) bfr[ks] = *(const bf16x8*)(wb + (ks << 5));
        float b2v = eb2[n0 + lr];
        for (int mt = 0; mt < 4; ++mt) {
            f32x4 acc = {0.f, 0.f, 0.f, 0.f};
            const bf16_t* pa = S + (mt * 16 + lr) * S_STRIDE + lk;
#pragma unroll
            for (int ks = 0; ks < 8; ++ks) {
                bf16x8 a = *(const bf16x8*)(pa + (ks << 5));
                acc = __builtin_amdgcn_mfma_f32_16x16x32_bf16(a, bfr[ks], acc, 0, 0, 0);
            }
            int rbase = mt * 16 + crb;
#pragma unroll
            for (int j = 0; j < 4; ++j) {
                int irow = rbase + j;
                int t = t0 + irow;
                float cnt = ((t >= 1) ? 1.f : 0.f) + ((t <= SEQ - 2) ? 1.f : 0.f);
                AGG[irow * S_STRIDE + n0 + lr] = (bf16_t)(acc[j] + cnt * b2v);
            }
        }
    }
    __syncthreads();

    // ---------- Phase 3: HN = relu(h @ nw1a + AGG @ nw1b + nb1) ----------
    for (int i = 0; i < 2; ++i) {
        int nt = (w << 1) + i;
        int n0 = nt << 4;
        bf16x8 ba[8], bb[8];
        const bf16_t* wba = wsw + WN1AT + ((n0 + lr) << 8) + lk;
        const bf16_t* wbb = wsw + WN1BT + ((n0 + lr) << 8) + lk;
#pragma unroll
        for (int ks = 0; ks < 8; ++ks) {
            ba[ks] = *(const bf16x8*)(wba + (ks << 5));
            bb[ks] = *(const bf16x8*)(wbb + (ks << 5));
        }
        float nb1v = nb1[n0 + lr];
        for (int mt = 0; mt < 4; ++mt) {
            f32x4 acc = {0.f, 0.f, 0.f, 0.f};
            const bf16_t* ph = hbf + (mt * 16 + 1 + lr) * HB_STRIDE + lk;  // +1: token row
            const bf16_t* pg = AGG + (mt * 16 + lr) * S_STRIDE + lk;
#pragma unroll
            for (int ks = 0; ks < 8; ++ks) {
                bf16x8 a = *(const bf16x8*)(ph + (ks << 5));
                acc = __builtin_amdgcn_mfma_f32_16x16x32_bf16(a, ba[ks], acc, 0, 0, 0);
            }
#pragma unroll
            for (int ks = 0; ks < 8; ++ks) {
                bf16x8 a = *(const bf16x8*)(pg + (ks << 5));
                acc = __builtin_amdgcn_mfma_f32_16x16x32_bf16(a, bb[ks], acc, 0, 0, 0);
            }
            int rbase = mt * 16 + crb;
#pragma unroll
            for (int j = 0; j < 4; ++j)
                HN[(rbase + j) * S_STRIDE + n0 + lr] = (bf16_t)fmaxf(acc[j] + nb1v, 0.f);
        }
    }
    __syncthreads();

    // ---------- Phase 4: out = h + mask * (HN @ nw2 + nb2) ----------
    for (int i = 0; i < 2; ++i) {
        int nt = (w << 1) + i;
        int n0 = nt << 4;
        bf16x8 bfr[8];
        const bf16_t* wb = wsw + WN2T + ((n0 + lr) << 8) + lk;
#pragma unroll
        for (int ks = 0; ks < 8; ++ks) bfr[ks] = *(const bf16x8*)(wb + (ks << 5));
        float nb2v = nb2[n0 + lr];
        for (int mt = 0; mt < 4; ++mt) {
            f32x4 acc = {0.f, 0.f, 0.f, 0.f};
            const bf16_t* pa = HN + (mt * 16 + lr) * S_STRIDE + lk;
#pragma unroll
            for (int ks = 0; ks < 8; ++ks) {
                bf16x8 a = *(const bf16x8*)(pa + (ks << 5));
                acc = __builtin_amdgcn_mfma_f32_16x16x32_bf16(a, bfr[ks], acc, 0, 0, 0);
            }
            int rbase = mt * 16 + crb;
#pragma unroll
            for (int j = 0; j < 4; ++j) {
                int irow = rbase + j;
                long t = baseTok + t0 + irow;
                long gaddr = (t << 8) + n0 + lr;
                float m = mask[t];
                out[gaddr] = h[gaddr] + m * (acc[j] + nb2v);
            }
        }
    }
}

extern "C" void kernel_launch(void* const* d_in, const int* in_sizes, int n_in,
                              void* d_out, int out_size, void* d_ws, size_t ws_size,
                              hipStream_t stream) {
    const float* h    = (const float*)d_in[0];
    const float* mask = (const float*)d_in[1];
    const float* ew1  = (const float*)d_in[2];
    const float* eb1  = (const float*)d_in[3];
    const float* ew2  = (const float*)d_in[4];
    const float* eb2  = (const float*)d_in[5];
    const float* nw1  = (const float*)d_in[6];
    const float* nb1  = (const float*)d_in[7];
    const float* nw2  = (const float*)d_in[8];
    const float* nb2  = (const float*)d_in[9];
    float* out   = (float*)d_out;
    bf16_t* wsw  = (bf16_t*)d_ws;

    // weight transpose+convert prepass (768 KiB in ws)
    wprep<<<WS_ELEMS / 256, 256, 0, stream>>>(ew1, ew2, nw1, nw2, wsw);

    // allow >64 KiB dynamic LDS (idempotent; host-side, graph-capture safe)
    hipFuncSetAttribute(reinterpret_cast<const void*>(gnl_kernel),
                        hipFuncAttributeMaxDynamicSharedMemorySize, SMEM_BYTES);

    gnl_kernel<<<BSZ * (SEQ / T_TOK), 512, SMEM_BYTES, stream>>>(
        h, mask, eb1, eb2, nb1, nb2, wsw, out);
}